// Round 4
// baseline (227.676 us; speedup 1.0000x reference)
//
#include <hip/hip_runtime.h>

typedef _Float16 f16;
typedef _Float16 f16x4 __attribute__((ext_vector_type(4)));
typedef _Float16 f16x8 __attribute__((ext_vector_type(8)));
typedef float    f32x4 __attribute__((ext_vector_type(4)));

#define B_ 4
#define T_ 2048
#define C_ 1024
#define H_ 16
#define D_ 64

__device__ __forceinline__ void gload_lds16(const f16* g, f16* l) {
  __builtin_amdgcn_global_load_lds(
      (const __attribute__((address_space(1))) unsigned int*)g,
      (__attribute__((address_space(3))) unsigned int*)l, 16, 0, 0);
}

// ---------------- prep kernels ----------------
__global__ void cvt_kernel(const float* __restrict__ in, f16* __restrict__ out, int n4) {
  int i = blockIdx.x * blockDim.x + threadIdx.x;
  int stride = gridDim.x * blockDim.x;
  for (; i < n4; i += stride) {
    float4 v = ((const float4*)in)[i];
    f16x4 h = { (f16)v.x, (f16)v.y, (f16)v.z, (f16)v.w };
    ((f16x4*)out)[i] = h;
  }
}

// Wt[n][k] = (f16)W[k][n]   (W is [K,N] row-major)
__global__ void transpose_cvt_kernel(const float* __restrict__ W, f16* __restrict__ Wt,
                                     int K, int N) {
  __shared__ f16 tile[32][33];
  int bx = blockIdx.x, by = blockIdx.y;
  int tx = threadIdx.x & 31, ty = threadIdx.x >> 5;  // 32 x 8
  #pragma unroll
  for (int i = ty; i < 32; i += 8)
    tile[i][tx] = (f16)W[(size_t)(by * 32 + i) * N + bx * 32 + tx];
  __syncthreads();
  #pragma unroll
  for (int i = ty; i < 32; i += 8)
    Wt[(size_t)(bx * 32 + i) * K + by * 32 + tx] = tile[tx][i];
}

// ---------------- GEMM: C = A[M,K] * Bt[N,K]^T + bias ----------------
// 128x128 tile, BK=32, TRIPLE-buffered LDS + counted vmcnt(4) (never 0 in
// main loop, T3/T4), raw s_barrier (1 per K-step), T2 XOR-swizzled LDS
// (linear gload_lds dest + pre-swizzled global src + swizzled ds_read,
// rule #21), T5 setprio around the MFMA cluster.
template <int EPI>
__global__ __launch_bounds__(256, 3)
void gemm_kernel(const f16* __restrict__ A, const f16* __restrict__ Bt,
                 const float* __restrict__ bias, float* __restrict__ outF,
                 f16* __restrict__ q, f16* __restrict__ kk, f16* __restrict__ vt,
                 int M, int N, int K) {
  __shared__ __align__(16) f16 As[3][128 * 32];
  __shared__ __align__(16) f16 Bs[3][128 * 32];
  const int nbn = N >> 7;
  const int bid = blockIdx.x;
  const int bm = bid / nbn, bn = bid % nbn;
  const int m0 = bm << 7, n0 = bn << 7;
  const int tid = threadIdx.x;
  const int lane = tid & 63, wid = tid >> 6;
  const int wr = wid >> 1, wc = wid & 1;

  f32x4 acc[4][4] = {};

  // staging: lane i covers LDS bytes chunk*1024 + i*16 (linear dest).
  // row = chunk*16 + (i>>2), phys 16B-slot cp = i&3. Pre-swizzle the SOURCE:
  // logical slot c_log = cp ^ (row&3) = (i&3) ^ ((i>>2)&3).
  const int srow = lane >> 2;
  const int scol = (((lane & 3) ^ ((lane >> 2) & 3)) << 3);  // f16 elems
  const f16* Abase = A + (size_t)(m0 + srow) * K + scol;
  const f16* Bbase = Bt + (size_t)(n0 + srow) * K + scol;

  auto stage = [&](int buf, int kt) {
    const int c0 = wid * 2;
    #pragma unroll
    for (int c = c0; c < c0 + 2; ++c) {
      gload_lds16(Abase + (size_t)c * 16 * K + kt * 32, &As[buf][c * 512]);
      gload_lds16(Bbase + (size_t)c * 16 * K + kt * 32, &Bs[buf][c * 512]);
    }
  };

  const int g = lane >> 4;       // 16B k-slot
  const int rr = lane & 15;
  const int swz = (g ^ (rr & 3)) << 4;  // swizzled byte slot (row&3 == rr&3)

  auto compute = [&](int buf) {
    f16x8 af[4], bf[4];
    #pragma unroll
    for (int t = 0; t < 4; ++t) {
      af[t] = *(const f16x8*)((const char*)&As[buf][0] + (wr * 64 + t * 16 + rr) * 64 + swz);
      bf[t] = *(const f16x8*)((const char*)&Bs[buf][0] + (wc * 64 + t * 16 + rr) * 64 + swz);
    }
    __builtin_amdgcn_s_setprio(1);
    #pragma unroll
    for (int i = 0; i < 4; ++i)
      #pragma unroll
      for (int j = 0; j < 4; ++j)
        acc[i][j] = __builtin_amdgcn_mfma_f32_16x16x32_f16(af[i], bf[j], acc[i][j], 0, 0, 0);
    __builtin_amdgcn_s_setprio(0);
  };

  const int nk = K >> 5;
  int bcur = 0, bnext = 1, bnn = 2;
  stage(0, 0);
  stage(1, 1);
  asm volatile("s_waitcnt vmcnt(4)" ::: "memory");
  __builtin_amdgcn_s_barrier();
  __builtin_amdgcn_sched_barrier(0);
  for (int t = 0; t < nk; ++t) {
    if (t + 2 < nk) stage(bnn, t + 2);
    compute(bcur);
    if (t + 1 < nk) {
      if (t + 2 < nk) asm volatile("s_waitcnt vmcnt(4)" ::: "memory");
      else            asm volatile("s_waitcnt vmcnt(0)" ::: "memory");
      __builtin_amdgcn_s_barrier();
      __builtin_amdgcn_sched_barrier(0);
    }
    const int tmp = bcur; bcur = bnext; bnext = bnn; bnn = tmp;
  }

  const int col = lane & 15;
  const int row4 = (lane >> 4) << 2;
  #pragma unroll
  for (int i = 0; i < 4; ++i) {
    #pragma unroll
    for (int j = 0; j < 4; ++j) {
      const int n = n0 + wc * 64 + j * 16 + col;
      const float bn_ = bias[n];
      #pragma unroll
      for (int r = 0; r < 4; ++r) {
        const int m = m0 + wr * 64 + i * 16 + row4 + r;
        const float v = acc[i][j][r] + bn_;
        if (EPI == 1) {
          outF[(size_t)m * N + n] = v;
        } else {
          const int which = n >> 10;           // 0=q 1=k 2=v
          const int cc = n & 1023;
          const int h = cc >> 6, d = cc & 63;
          const int b = m >> 11, t = m & 2047;
          const size_t bh = (size_t)b * 16 + h;
          const f16 hv = (f16)v;
          if (which == 0)      q [(bh * T_ + t) * D_ + d] = hv;
          else if (which == 1) kk[(bh * T_ + t) * D_ + d] = hv;
          else                 vt[(bh * D_ + d) * T_ + t] = hv;  // V transposed
        }
      }
    }
  }
}

// ---------------- causal flash attention (unchanged from round 3) ----------------
__global__ __launch_bounds__(512, 2)
void attn_kernel(const f16* __restrict__ Q, const f16* __restrict__ Kg,
                 const f16* __restrict__ Vt, f16* __restrict__ Aout) {
  __shared__ __align__(16) f16 Ks[2][64 * 64];   // [kvrow][d], rows 128B, swizzled
  __shared__ __align__(16) f16 Vs[2][64 * 64];   // [d][kv],   rows 128B, swizzled
  __shared__ __align__(16) f16 Pt[8][16][72];    // per-wave P^T tile [q][kv], +8 pad

  const int bid = blockIdx.x;
  const int wgid = (bid & 7) * 128 + (bid >> 3);
  const int bh = wgid >> 4;
  const int ti = 15 - (wgid & 15);
  const int lane = threadIdx.x & 63, w = threadIdx.x >> 6;
  const int col = lane & 15;
  const int g = lane >> 4;
  const int ko = g << 3;

  const f16* Qp = Q + (size_t)bh * T_ * D_;
  const f16* Kp = Kg + (size_t)bh * T_ * D_;
  const f16* Vp = Vt + (size_t)bh * D_ * T_;

  const int srow8 = lane >> 3;
  const int scb = ((lane & 7) << 4) ^ (srow8 << 4);
  const int krow_s = (w << 3) + srow8;

  auto stage = [&](int buf, int kb) {
    gload_lds16(Kp + (size_t)(kb + krow_s) * D_ + (scb >> 1), &Ks[buf][w * 512]);
    gload_lds16(Vp + (size_t)krow_s * T_ + kb + (scb >> 1), &Vs[buf][w * 512]);
  };
  auto ldsK = [&](int buf, int krow, int d0) -> f16x8 {
    const int off = krow * 128 + ((d0 << 1) ^ ((krow & 7) << 4));
    return *(const f16x8*)((const char*)&Ks[buf][0] + off);
  };
  auto ldsV = [&](int buf, int drow, int k0) -> f16x8 {
    const int off = drow * 128 + ((k0 << 1) ^ ((drow & 7) << 4));
    return *(const f16x8*)((const char*)&Vs[buf][0] + off);
  };

  const int q0 = ti << 7;
  const int qrow0 = q0 + (w << 4);
  const int nkt = (ti << 1) + 2;
  const int qg = qrow0 + col;

  f16x8 qf[2];
  #pragma unroll
  for (int s = 0; s < 2; ++s) {
    f16x8 t = *(const f16x8*)&Qp[(size_t)qg * D_ + s * 32 + ko];
    #pragma unroll
    for (int e = 0; e < 8; ++e) t[e] = t[e] * (f16)0.125f;
    qf[s] = t;
  }

  f32x4 o[4] = {};
  float m = -1e30f, l = 0.f;

  stage(0, 0);
  __syncthreads();
  int cur = 0;
  for (int kt = 0; kt < nkt; ++kt) {
    const int kb = kt << 6;
    if (kt + 1 < nkt) stage(cur ^ 1, (kt + 1) << 6);

    if (kb <= qrow0 + 15) {
      f32x4 sc[4] = {};
      #pragma unroll
      for (int s = 0; s < 2; ++s)
        #pragma unroll
        for (int mt = 0; mt < 4; ++mt) {
          f16x8 kf = ldsK(cur, mt * 16 + col, s * 32 + ko);
          sc[mt] = __builtin_amdgcn_mfma_f32_16x16x32_f16(kf, qf[s], sc[mt], 0, 0, 0);
        }

      const bool needMask = (kb + 63 > qrow0);
      if (needMask) {
        #pragma unroll
        for (int mt = 0; mt < 4; ++mt)
          #pragma unroll
          for (int r = 0; r < 4; ++r)
            if (kb + mt * 16 + (g << 2) + r > qg) sc[mt][r] = -1e30f;
      }

      float mx = fmaxf(fmaxf(fmaxf(sc[0][0], sc[0][1]), fmaxf(sc[0][2], sc[0][3])),
                       fmaxf(fmaxf(sc[1][0], sc[1][1]), fmaxf(sc[1][2], sc[1][3])));
      mx = fmaxf(mx, fmaxf(fmaxf(fmaxf(sc[2][0], sc[2][1]), fmaxf(sc[2][2], sc[2][3])),
                           fmaxf(fmaxf(sc[3][0], sc[3][1]), fmaxf(sc[3][2], sc[3][3]))));
      mx = fmaxf(mx, __shfl_xor(mx, 16, 64));
      mx = fmaxf(mx, __shfl_xor(mx, 32, 64));

      if (!__all(mx - m <= 8.f)) {
        const float mnew = fmaxf(m, mx);
        const float alpha = __expf(m - mnew);
        m = mnew;
        l *= alpha;
        #pragma unroll
        for (int mt = 0; mt < 4; ++mt)
          #pragma unroll
          for (int r = 0; r < 4; ++r) o[mt][r] *= alpha;
      }

      float rs = 0.f;
      #pragma unroll
      for (int mt = 0; mt < 4; ++mt) {
        f16x4 ph;
        #pragma unroll
        for (int r = 0; r < 4; ++r) {
          const float p = __expf(sc[mt][r] - m);
          rs += p;
          ph[r] = (f16)p;
        }
        *(f16x4*)&Pt[w][col][mt * 16 + (g << 2)] = ph;
      }
      rs += __shfl_xor(rs, 16, 64);
      rs += __shfl_xor(rs, 32, 64);
      l += rs;

      #pragma unroll
      for (int s = 0; s < 2; ++s) {
        f16x8 pb = *(const f16x8*)&Pt[w][col][s * 32 + ko];
        #pragma unroll
        for (int mt = 0; mt < 4; ++mt) {
          f16x8 vf = ldsV(cur, mt * 16 + col, s * 32 + ko);
          o[mt] = __builtin_amdgcn_mfma_f32_16x16x32_f16(vf, pb, o[mt], 0, 0, 0);
        }
      }
    }

    __syncthreads();
    cur ^= 1;
  }

  const int b = bh >> 4, h = bh & 15;
  const float inv = 1.0f / l;
  const size_t rowoff = ((size_t)b * T_ + qg) * C_ + (size_t)h * D_;
  #pragma unroll
  for (int mt = 0; mt < 4; ++mt) {
    f16x4 ov;
    #pragma unroll
    for (int r = 0; r < 4; ++r) ov[r] = (f16)(o[mt][r] * inv);
    *(f16x4*)&Aout[rowoff + mt * 16 + (g << 2)] = ov;
  }
}

// ---------------- launch ----------------
extern "C" void kernel_launch(void* const* d_in, const int* in_sizes, int n_in,
                              void* d_out, int out_size, void* d_ws, size_t ws_size,
                              hipStream_t stream) {
  const float* x    = (const float*)d_in[0];
  const float* Wqkv = (const float*)d_in[1];
  const float* bqkv = (const float*)d_in[2];
  const float* Wout = (const float*)d_in[3];
  const float* bout = (const float*)d_in[4];
  float* out = (float*)d_out;

  char* ws = (char*)d_ws;
  f16* xb     = (f16*)ws;                   // 16MB (x in f16; later reused as Aout)
  f16* Wqkv_t = (f16*)(ws + (16u << 20));   // 6MB  [3072,1024]
  f16* Wout_t = (f16*)(ws + (22u << 20));   // 2MB  [1024,1024]
  f16* Qb     = (f16*)(ws + (24u << 20));   // 16MB [B,H,T,D]
  f16* Kb     = (f16*)(ws + (40u << 20));   // 16MB [B,H,T,D]
  f16* Vtb    = (f16*)(ws + (56u << 20));   // 16MB [B,H,D,T]

  cvt_kernel<<<2048, 256, 0, stream>>>(x, xb, (B_ * T_ * C_) / 4);
  dim3 g1(3072 / 32, 1024 / 32);
  transpose_cvt_kernel<<<g1, 256, 0, stream>>>(Wqkv, Wqkv_t, 1024, 3072);
  dim3 g2(1024 / 32, 1024 / 32);
  transpose_cvt_kernel<<<g2, 256, 0, stream>>>(Wout, Wout_t, 1024, 1024);

  gemm_kernel<0><<<64 * 24, 256, 0, stream>>>(xb, Wqkv_t, bqkv, nullptr,
                                              Qb, Kb, Vtb, 8192, 3072, 1024);
  attn_kernel<<<1024, 512, 0, stream>>>(Qb, Kb, Vtb, xb /*Aout alias*/);
  gemm_kernel<1><<<64 * 8, 256, 0, stream>>>(xb, Wout_t, bout, out,
                                             nullptr, nullptr, nullptr, 8192, 1024, 1024);
}